// Round 9
// baseline (123.909 us; speedup 1.0000x reference)
//
#include <hip/hip_runtime.h>
#include <hip/hip_fp16.h>
#include <math.h>

// WaveNet collapsed to the last time column (symmetric pad (K-1)*d puts the
// k=1 tap of every dilated conv in the zero pad at the final position).
// ONE kernel + a 96-byte memset. Sparse DAG sync via 3 monotonic counters
// (R5/R7 showed dense per-item flags are catastrophic; this uses ~90 releases
// and ~80 polling waves total). Weight preloads for the skip/end phases
// overlap the fold+recurrence critical path.
//   blocks 0..79  : fold M_{f,g}[l] = W_{f,g}[l](Wr_{l-1}+I) -> fp16 blob
//   block  80     : start conv -> c0, zero hsum
//   blocks 81..88 : per-batch 40-layer recurrence (1 wave), z' = tanh*sig
//   blocks 89..128: per-layer skip matvec (weights preloaded), all 8 batches
//   blocks 129..160: per-(batch,quarter) end1+end2, last arriver writes out

#define NL 40
#define TLEN 8192

// ws float-offset layout
#define F_BLOB 0        // fp16 [40][64 lanes][32 halfs] = 81920 halfs
#define F_C0   40960    // [8][32]
#define F_Z    41216    // [40][8][32]  (= l*256 + b*32 + ch)
#define F_H    51456    // [8][256] skip accumulator
#define F_SYNC 53504    // ints: cnt1,cnt2,cnt3,pad | floats obuf[8] | cnt4[8]
#define SYNC_BYTE_OFF (F_SYNC * 4)
#define SYNC_BYTES 96

typedef __attribute__((ext_vector_type(2))) _Float16 h2;

#if defined(__has_builtin)
#if __has_builtin(__builtin_amdgcn_fdot2)
#define HAS_FDOT2 1
#endif
#endif

__device__ __forceinline__ float FDOT2(h2 a, h2 b, float c) {
#ifdef HAS_FDOT2
    return __builtin_amdgcn_fdot2(a, b, c, false);
#else
    return c + (float)a.x * (float)b.x + (float)a.y * (float)b.y;
#endif
}

__device__ __forceinline__ float tanh_fast(float f) {
    f = fminf(fmaxf(f, -15.f), 15.f);
    float e2 = __expf(2.f * f);
    return (e2 - 1.f) / (e2 + 1.f);
}

__device__ __forceinline__ void rel_cnt(int* p) {
    __hip_atomic_fetch_add(p, 1, __ATOMIC_ACQ_REL, __HIP_MEMORY_SCOPE_AGENT);
}
__device__ __forceinline__ void wait_cnt(const int* p, int target) {
    while (__hip_atomic_load(p, __ATOMIC_ACQUIRE, __HIP_MEMORY_SCOPE_AGENT)
           < target)
        __builtin_amdgcn_s_sleep(8);
}

// --------------------------- K2 recurrence macros (R8-proven) -------------
#define K2_PREF(L, W) do {                                                   \
    if ((L) < NL) {                                                          \
        _Pragma("unroll")                                                    \
        for (int i = 0; i < 4; ++i)                                          \
            W[i] = blob[(L) * 256 + lane * 4 + i];                           \
    }                                                                        \
} while (0)

#define K2_STEP(L, W) do {                                                   \
    h2 s[8];                                                                 \
    { const float4* sp = (const float4*)zsm;                                 \
      *(float4*)&s[0] = sp[h * 2];                                           \
      *(float4*)&s[4] = sp[h * 2 + 1]; }                                     \
    float f = 0.f, g = 0.f;                                                  \
    const h2* wfp = (const h2*)&W[0];                                        \
    const h2* wgp = (const h2*)&W[2];                                        \
    _Pragma("unroll")                                                        \
    for (int i = 0; i < 8; ++i) {                                            \
        f = FDOT2(wfp[i], s[i], f);                                          \
        g = FDOT2(wgp[i], s[i], g);                                          \
    }                                                                        \
    f += __shfl_xor(f, 32, 64);                                              \
    g += __shfl_xor(g, 32, 64);                                              \
    float z = tanh_fast(f) * (1.f / (1.f + __expf(-g)));                     \
    if (h == 0) {                                                            \
        zbuf[(L) * 256 + b * 32 + ch] = z;                                   \
        zsm[ch] = __float2half(z);                                           \
    }                                                                        \
    __builtin_amdgcn_wave_barrier();                                         \
    K2_PREF((L) + 4, W);                                                     \
} while (0)

__global__ __launch_bounds__(256) void wavenet_mega(
    const float* __restrict__ x, const float* __restrict__ start_w,
    const float* __restrict__ filter_w, const float* __restrict__ gate_w,
    const float* __restrict__ res_w, const float* __restrict__ skip_w,
    const float* __restrict__ end1_w, const float* __restrict__ end1_b,
    const float* __restrict__ end2_w, const float* __restrict__ end2_b,
    float* __restrict__ ws, float* __restrict__ out)
{
    const int id = blockIdx.x, t = threadIdx.x;
    int*   cnt1 = (int*)(ws + F_SYNC);
    int*   cnt2 = cnt1 + 1;
    int*   cnt3 = cnt1 + 2;
    float* obuf = ws + F_SYNC + 8;
    int*   cnt4 = (int*)(ws + F_SYNC + 16);
    float* zbuf = ws + F_Z;
    float* hsum = ws + F_H;

    if (id < 80) {
        // ---------------- fold: M = F * (R_{l-1} + I) -> fp16 blob --------
        const int l = id >> 1, m = id & 1;
        __shared__ float F[32][32];
        __shared__ __align__(16) float R[32][36];
        const float* src = m ? gate_w : filter_w;
        for (int e = t; e < 1024; e += 256)
            F[e >> 5][e & 31] = src[(l * 1024 + e) * 2];   // k=0 taps
        if (l > 0)
            for (int e = t; e < 1024; e += 256) {
                const int k = e >> 5, j = e & 31;
                R[k][j] = res_w[(l - 1) * 1024 + e] + (k == j ? 1.f : 0.f);
            }
        __syncthreads();
        const int ch = t >> 3, jg = t & 7, j0 = jg * 4;
        float o0, o1, o2, o3;
        if (l == 0) {
            o0 = F[ch][j0]; o1 = F[ch][j0+1]; o2 = F[ch][j0+2]; o3 = F[ch][j0+3];
        } else {
            o0 = o1 = o2 = o3 = 0.f;
#pragma unroll
            for (int k = 0; k < 32; ++k) {
                const float fv = F[ch][k];
                const float4 rv = *(const float4*)&R[k][j0];
                o0 += fv*rv.x; o1 += fv*rv.y; o2 += fv*rv.z; o3 += fv*rv.w;
            }
        }
        const int hh = jg >> 2;
        __half* dst = (__half*)ws + (size_t)l * 2048 + (hh * 32 + ch) * 32
                    + (m ? 16 : 0) + (j0 & 15);
        ((__half2*)dst)[0] = __floats2half2_rn(o0, o1);
        ((__half2*)dst)[1] = __floats2half2_rn(o2, o3);
        __syncthreads();
        if (t == 0) rel_cnt(cnt1);
    }
    else if (id == 80) {
        // ---------------- prep: start conv + zero hsum --------------------
        const int b = t >> 5, ch = t & 31;
        float acc = 0.f;
#pragma unroll
        for (int j = 0; j < 6; ++j)
            acc += start_w[ch * 6 + j] * x[(b * 6 + j) * TLEN + TLEN - 1];
        ws[F_C0 + t] = acc;
#pragma unroll
        for (int k = t; k < 2048; k += 256) hsum[k] = 0.f;
        __syncthreads();
        if (t == 0) rel_cnt(cnt1);
    }
    else if (id < 89) {
        // ---------------- recurrence, batch b, wave 0 only ----------------
        if (t >= 64) return;
        const int b = id - 81;
        const int lane = t;
        const int ch = lane & 31, h = lane >> 5;
        __shared__ __align__(16) __half zsm[32];

        wait_cnt(cnt1, 81);                     // whole wave polls (1 ld/iter)

        if (h == 0) zsm[ch] = __float2half(ws[F_C0 + b * 32 + ch]);
        __builtin_amdgcn_wave_barrier();

        const float4* blob = (const float4*)ws;
        float4 w0[4], w1[4], w2[4], w3[4];
        K2_PREF(0, w0); K2_PREF(1, w1); K2_PREF(2, w2); K2_PREF(3, w3);
        for (int l = 0; l < NL; l += 4) {
            K2_STEP(l + 0, w0);
            K2_STEP(l + 1, w1);
            K2_STEP(l + 2, w2);
            K2_STEP(l + 3, w3);
        }
        if (lane == 0) rel_cnt(cnt2);
    }
    else if (id < 129) {
        // ---------------- skip matvec, layer l, all 8 batches -------------
        const int l = id - 89;
        __shared__ __align__(16) float zsm[256];
        float4 wreg[8];                          // preload BEFORE waiting
        const float4* wp = (const float4*)(skip_w + (size_t)(l * 256 + t) * 32);
#pragma unroll
        for (int i = 0; i < 8; ++i) wreg[i] = wp[i];

        wait_cnt(cnt2, 8);
        zsm[t] = zbuf[l * 256 + t];              // [b][ch] for this layer
        __syncthreads();
#pragma unroll
        for (int b = 0; b < 8; ++b) {
            const float4* z4 = (const float4*)(zsm + b * 32);
            float acc = 0.f;
#pragma unroll
            for (int i = 0; i < 8; ++i) {
                float4 wv = wreg[i], zv = z4[i];
                acc += wv.x*zv.x + wv.y*zv.y + wv.z*zv.z + wv.w*zv.w;
            }
            atomicAdd(&hsum[b * 256 + t], acc);
        }
        __syncthreads();
        if (t == 0) rel_cnt(cnt3);
    }
    else {
        // ---------------- end1 + end2, (batch b, quarter q) ---------------
        const int e = id - 129, b = e >> 2, q = e & 3;
        const int p = t >> 6, oc = t & 63, row = q * 64 + oc;
        __shared__ __align__(16) float hsm[256];
        __shared__ float psum[64][5];

        float4 wreg[16];                         // preload BEFORE waiting
        const float4* wp = (const float4*)(end1_w + (size_t)row * 256 + p * 64);
#pragma unroll
        for (int i = 0; i < 16; ++i) wreg[i] = wp[i];

        wait_cnt(cnt3, 40);
        hsm[t] = fmaxf(hsum[b * 256 + t], 0.f);  // relu(skip_sum)
        __syncthreads();
        const float4* h4 = (const float4*)(hsm + p * 64);
        float acc = 0.f;
#pragma unroll
        for (int i = 0; i < 16; ++i) {
            float4 wv = wreg[i], hv = h4[i];
            acc += wv.x*hv.x + wv.y*hv.y + wv.z*hv.z + wv.w*hv.w;
        }
        psum[oc][p] = acc;
        __syncthreads();
        if (t < 64) {
            const int rr = q * 64 + t;
            float ev = psum[t][0] + psum[t][1] + psum[t][2] + psum[t][3]
                     + end1_b[rr];
            ev = fmaxf(ev, 0.f);
            float pe = ev * end2_w[rr];
#pragma unroll
            for (int off = 32; off > 0; off >>= 1)
                pe += __shfl_down(pe, off, 64);
            if (t == 0) {
                atomicAdd(&obuf[b], pe);
                __threadfence();
                int old = __hip_atomic_fetch_add(&cnt4[b], 1, __ATOMIC_ACQ_REL,
                                                 __HIP_MEMORY_SCOPE_AGENT);
                if (old == 3) {
                    float tot = __hip_atomic_load(&obuf[b], __ATOMIC_ACQUIRE,
                                                  __HIP_MEMORY_SCOPE_AGENT);
                    out[b] = tot + end2_b[0];
                }
            }
        }
    }
}

extern "C" void kernel_launch(void* const* d_in, const int* in_sizes, int n_in,
                              void* d_out, int out_size, void* d_ws, size_t ws_size,
                              hipStream_t stream) {
    const float* x        = (const float*)d_in[0];
    const float* start_w  = (const float*)d_in[1];
    const float* filter_w = (const float*)d_in[2];
    const float* gate_w   = (const float*)d_in[3];
    const float* res_w    = (const float*)d_in[4];
    const float* skip_w   = (const float*)d_in[5];
    const float* end1_w   = (const float*)d_in[6];
    const float* end1_b   = (const float*)d_in[7];
    const float* end2_w   = (const float*)d_in[8];
    const float* end2_b   = (const float*)d_in[9];
    float* out = (float*)d_out;
    float* ws  = (float*)d_ws;

    hipMemsetAsync((char*)d_ws + SYNC_BYTE_OFF, 0, SYNC_BYTES, stream);
    wavenet_mega<<<161, 256, 0, stream>>>(
        x, start_w, filter_w, gate_w, res_w, skip_w,
        end1_w, end1_b, end2_w, end2_b, ws, out);
}

// Round 10
// 106.863 us; speedup vs baseline: 1.1595x; 1.1595x over previous
//
#include <hip/hip_runtime.h>
#include <hip/hip_fp16.h>
#include <math.h>

// WaveNet collapsed to the last time column (symmetric pad (K-1)*d puts the
// k=1 tap of every dilated conv in the zero pad at the final position).
// TWO flag-free kernels (R5/R7/R9 all measured: ANY cross-workgroup sync —
// dense flags, bounded flags, sparse counters — loses to kernel boundaries).
//   K1 (305 blocks): fold M_{f,g}[l] = W_{f,g}[l](Wr_{l-1}+I) -> fp16 blob;
//       cast skip_w -> fp16 (same layout); cast end1_w -> fp16 TRANSPOSED
//       [sc2][ec] for coalesced epilogue reads; start conv -> c0.
//   K2 (8 blocks x 320): block b owns batch b end-to-end.
//       wave0: serial 40-layer recurrence z' = tanh(Mf z)*sig(Mg z).
//       waves1-4 (lane=skip channel sc): consume z_{l-1} each layer via a
//       double-buffered LDS ring + one __syncthreads per layer (intra-block
//       sync is cheap), skip_acc in registers. Epilogue: relu -> end1(fp16,
//       from L2) -> end2 -> out[b]. No atomics, no flags, no hsum.

#define NL 40
#define TLEN 8192

// ws float-offset layout
#define F_BLOBFG 0        // fp16 [40][64 lanes][32] = 81920 halfs = 40960 fl
#define F_BLOBSK 40960    // fp16 [40][256 sc][32]  = 327680 halfs
#define F_BLOBE1 204800   // fp16 [128 sc2][256 ec] half2 = 65536 halfs
#define F_C0     237568   // [8][32] fp32

typedef __attribute__((ext_vector_type(2))) _Float16 h2;

#if defined(__has_builtin)
#if __has_builtin(__builtin_amdgcn_fdot2)
#define HAS_FDOT2 1
#endif
#endif

__device__ __forceinline__ float FDOT2(h2 a, h2 b, float c) {
#ifdef HAS_FDOT2
    return __builtin_amdgcn_fdot2(a, b, c, false);
#else
    return c + (float)a.x * (float)b.x + (float)a.y * (float)b.y;
#endif
}

__device__ __forceinline__ float tanh_fast(float f) {
    f = fminf(fmaxf(f, -15.f), 15.f);
    float e2 = __expf(2.f * f);
    return (e2 - 1.f) / (e2 + 1.f);
}

// ---------------------------------------------------- K1: repack everything
__global__ __launch_bounds__(256) void k1_prep(
    const float* __restrict__ x, const float* __restrict__ start_w,
    const float* __restrict__ filter_w, const float* __restrict__ gate_w,
    const float* __restrict__ res_w, const float* __restrict__ skip_w,
    const float* __restrict__ end1_w, float* __restrict__ ws)
{
    const int id = blockIdx.x, t = threadIdx.x;

    if (id < 80) {
        // fold: M = F * (R_{l-1} + I) -> fp16 blob (R8-proven)
        const int l = id >> 1, m = id & 1;
        __shared__ float F[32][32];
        __shared__ __align__(16) float R[32][36];
        const float* src = m ? gate_w : filter_w;
        for (int e = t; e < 1024; e += 256)
            F[e >> 5][e & 31] = src[(l * 1024 + e) * 2];   // k=0 taps
        if (l > 0)
            for (int e = t; e < 1024; e += 256) {
                const int k = e >> 5, j = e & 31;
                R[k][j] = res_w[(l - 1) * 1024 + e] + (k == j ? 1.f : 0.f);
            }
        __syncthreads();
        const int ch = t >> 3, jg = t & 7, j0 = jg * 4;
        float o0, o1, o2, o3;
        if (l == 0) {
            o0 = F[ch][j0]; o1 = F[ch][j0+1]; o2 = F[ch][j0+2]; o3 = F[ch][j0+3];
        } else {
            o0 = o1 = o2 = o3 = 0.f;
#pragma unroll
            for (int k = 0; k < 32; ++k) {
                const float fv = F[ch][k];
                const float4 rv = *(const float4*)&R[k][j0];
                o0 += fv*rv.x; o1 += fv*rv.y; o2 += fv*rv.z; o3 += fv*rv.w;
            }
        }
        const int hh = jg >> 2;
        __half* dst = (__half*)ws + (size_t)l * 2048 + (hh * 32 + ch) * 32
                    + (m ? 16 : 0) + (j0 & 15);
        ((__half2*)dst)[0] = __floats2half2_rn(o0, o1);
        ((__half2*)dst)[1] = __floats2half2_rn(o2, o3);
    }
    else if (id == 80) {
        // start conv -> c0
        const int b = t >> 5, ch = t & 31;
        float acc = 0.f;
#pragma unroll
        for (int j = 0; j < 6; ++j)
            acc += start_w[ch * 6 + j] * x[(b * 6 + j) * TLEN + TLEN - 1];
        ws[F_C0 + t] = acc;
    }
    else if (id < 241) {
        // skip_w -> fp16, identical layout. 160 blocks x 256 thr x 8 floats.
        const int q = (id - 81) * 256 + t;           // 0..40959
        const float4* s4 = (const float4*)skip_w;
        const float4 a = s4[q * 2], bb = s4[q * 2 + 1];
        __half2* d = (__half2*)(ws + F_BLOBSK);
        d[q * 4 + 0] = __floats2half2_rn(a.x,  a.y);
        d[q * 4 + 1] = __floats2half2_rn(a.z,  a.w);
        d[q * 4 + 2] = __floats2half2_rn(bb.x, bb.y);
        d[q * 4 + 3] = __floats2half2_rn(bb.z, bb.w);
    }
    else {
        // end1_w -> fp16 transposed: half2[sc2][ec]. 64 blocks x 512 entries.
        __half2* d = (__half2*)(ws + F_BLOBE1);
#pragma unroll
        for (int k = 0; k < 2; ++k) {
            const int dd = (id - 241) * 512 + k * 256 + t;
            const int ec = dd & 255, sc2 = dd >> 8;
            const float v0 = end1_w[ec * 256 + 2 * sc2];
            const float v1 = end1_w[ec * 256 + 2 * sc2 + 1];
            d[dd] = __floats2half2_rn(v0, v1);
        }
    }
}

// -------------------------------- K2: recurrence + skip + end, one block/batch
#define PF(L, W) do {                                                        \
    if ((L) < NL) {                                                          \
        _Pragma("unroll")                                                    \
        for (int i = 0; i < 4; ++i)                                          \
            W[i] = blobfg[(L) * 256 + lane * 4 + i];                         \
    }                                                                        \
} while (0)

#define SPF(L, SW) do {                                                      \
    if ((L) < NL) {                                                          \
        _Pragma("unroll")                                                    \
        for (int i = 0; i < 4; ++i)                                          \
            SW[i] = blobsk[(L) * 1024 + sc * 4 + i];                         \
    }                                                                        \
} while (0)

// one layer: wave0 computes z_L; consumers eat z_{L-1}; single barrier
#define BODY(L, FG, SW) do {                                                 \
    if (wv == 0) {                                                           \
        h2 s[8];                                                             \
        { const float4* sp = (const float4*)zown;                            \
          *(float4*)&s[0] = sp[h * 2];                                       \
          *(float4*)&s[4] = sp[h * 2 + 1]; }                                 \
        float f = 0.f, g = 0.f;                                              \
        const h2* wfp = (const h2*)&FG[0];                                   \
        const h2* wgp = (const h2*)&FG[2];                                   \
        _Pragma("unroll")                                                    \
        for (int i = 0; i < 8; ++i) {                                        \
            f = FDOT2(wfp[i], s[i], f);                                      \
            g = FDOT2(wgp[i], s[i], g);                                      \
        }                                                                    \
        f += __shfl_xor(f, 32, 64);                                          \
        g += __shfl_xor(g, 32, 64);                                          \
        const float z = tanh_fast(f) * (1.f / (1.f + __expf(-g)));           \
        const __half hz = __float2half(z);                                   \
        if (h == 0) { zown[ch] = hz; zring[(L) & 1][ch] = hz; }              \
        PF((L) + 4, FG);                                                     \
    } else {                                                                 \
        if ((L) >= 1) {                                                      \
            const h2* zr2 = (const h2*)zring[((L) - 1) & 1];                 \
            const h2* wp  = (const h2*)SW;                                   \
            _Pragma("unroll")                                                \
            for (int i = 0; i < 16; ++i)                                     \
                skip_acc = FDOT2(wp[i], zr2[i], skip_acc);                   \
        }                                                                    \
        SPF((L) + 1, SW);                                                    \
    }                                                                        \
    __syncthreads();                                                         \
} while (0)

__global__ __launch_bounds__(320) void k2_all(
    const float* __restrict__ end1_b, const float* __restrict__ end2_w,
    const float* __restrict__ end2_b, const float* __restrict__ ws,
    float* __restrict__ out)
{
    const int b = blockIdx.x, t = threadIdx.x;
    const int wv = t >> 6, lane = t & 63;
    const int ch = lane & 31, h = lane >> 5;
    const int sc = t - 64;                    // consumer skip channel (wv>=1)

    __shared__ __align__(16) __half zown[32];
    __shared__ __align__(16) __half zring[2][32];
    __shared__ __align__(16) __half hhalf[256];
    __shared__ float psum[4];

    const float4* blobfg = (const float4*)ws;
    const float4* blobsk = (const float4*)(ws + F_BLOBSK);
    const h2*     blobe1 = (const h2*)(ws + F_BLOBE1);

    float4 fg0[4], fg1[4], fg2[4], fg3[4];
    float4 sw0[4], sw1[4];
    float skip_acc = 0.f, b1 = 0.f, w2 = 0.f;

    if (wv == 0) {
        if (h == 0) zown[ch] = __float2half(ws[F_C0 + b * 32 + ch]);
        PF(0, fg0); PF(1, fg1); PF(2, fg2); PF(3, fg3);
    } else {
        b1 = end1_b[sc];
        w2 = end2_w[sc];
        SPF(0, sw0);
    }
    __syncthreads();

    for (int l = 0; l < NL; l += 4) {
        BODY(l + 0, fg0, sw1);
        BODY(l + 1, fg1, sw0);
        BODY(l + 2, fg2, sw1);
        BODY(l + 3, fg3, sw0);
    }

    // consume the last layer's z (layer 39, slot 1, weights in sw1)
    if (wv >= 1) {
        const h2* zr2 = (const h2*)zring[1];
        const h2* wp  = (const h2*)sw1;
#pragma unroll
        for (int i = 0; i < 16; ++i)
            skip_acc = FDOT2(wp[i], zr2[i], skip_acc);
        hhalf[sc] = __float2half(fmaxf(skip_acc, 0.f));   // relu(skip_sum)
    }
    __syncthreads();

    // end1 (fp16 from L2, coalesced) + relu + end2 partial
    if (wv >= 1) {
        float acc = b1;
        const h2* hh2 = (const h2*)hhalf;
#pragma unroll 8
        for (int s2 = 0; s2 < 128; ++s2)
            acc = FDOT2(blobe1[s2 * 256 + sc], hh2[s2], acc);
        float pe = fmaxf(acc, 0.f) * w2;
#pragma unroll
        for (int off = 32; off > 0; off >>= 1)
            pe += __shfl_down(pe, off, 64);
        if (lane == 0) psum[wv - 1] = pe;
    }
    __syncthreads();
    if (t == 64)
        out[b] = psum[0] + psum[1] + psum[2] + psum[3] + end2_b[0];
}

extern "C" void kernel_launch(void* const* d_in, const int* in_sizes, int n_in,
                              void* d_out, int out_size, void* d_ws, size_t ws_size,
                              hipStream_t stream) {
    const float* x        = (const float*)d_in[0];
    const float* start_w  = (const float*)d_in[1];
    const float* filter_w = (const float*)d_in[2];
    const float* gate_w   = (const float*)d_in[3];
    const float* res_w    = (const float*)d_in[4];
    const float* skip_w   = (const float*)d_in[5];
    const float* end1_w   = (const float*)d_in[6];
    const float* end1_b   = (const float*)d_in[7];
    const float* end2_w   = (const float*)d_in[8];
    const float* end2_b   = (const float*)d_in[9];
    float* out = (float*)d_out;
    float* ws  = (float*)d_ws;

    k1_prep<<<305, 256, 0, stream>>>(x, start_w, filter_w, gate_w, res_w,
                                     skip_w, end1_w, ws);
    k2_all <<<8, 320, 0, stream>>>(end1_b, end2_w, end2_b, ws, out);
}

// Round 11
// 102.018 us; speedup vs baseline: 1.2146x; 1.0475x over previous
//
#include <hip/hip_runtime.h>
#include <hip/hip_fp16.h>
#include <math.h>

// WaveNet collapsed to the last time column (symmetric pad (K-1)*d puts the
// k=1 tap of every dilated conv in the zero pad at the final position).
// TWO flag-free kernels. Cross-workgroup sync via global flags measured 3x
// catastrophic (R5/R7/R9) -> only kernel boundaries between blocks.
// R10's intra-block fusion paced the serial wave by consumer global loads
// through per-layer __syncthreads; R11 decouples via an LDS-only progress
// counter: wave0 free-runs, consumers self-pace (LDS polling = no L2 traffic).
//   K1 (305 blocks): fold M_{f,g}[l]=W_{f,g}[l](Wr_{l-1}+I) -> fp16 blob;
//       skip_w -> fp16; end1_w -> fp16 transposed [sc2][ec]; start conv.
//   K2 (8 blocks x 320): block b owns batch b end-to-end.
//       wave0: serial 40-layer recurrence into a 41-slot LDS z-ring,
//              volatile LDS counter bump per layer (never waits).
//       waves1-4: poll counter, skip matvec with 2-deep weight prefetch,
//              then relu -> end1(fp16 from L2) -> end2 -> out[b].

#define NL 40
#define TLEN 8192

// ws float-offset layout
#define F_BLOBFG 0        // fp16 [40][64 lanes][32] = 81920 halfs
#define F_BLOBSK 40960    // fp16 [40][256 sc][32]  = 327680 halfs
#define F_BLOBE1 204800   // fp16 half2[128 sc2][256 ec] = 65536 halfs
#define F_C0     237568   // [8][32] fp32

typedef __attribute__((ext_vector_type(2))) _Float16 h2;

#if defined(__has_builtin)
#if __has_builtin(__builtin_amdgcn_fdot2)
#define HAS_FDOT2 1
#endif
#endif

__device__ __forceinline__ float FDOT2(h2 a, h2 b, float c) {
#ifdef HAS_FDOT2
    return __builtin_amdgcn_fdot2(a, b, c, false);
#else
    return c + (float)a.x * (float)b.x + (float)a.y * (float)b.y;
#endif
}

__device__ __forceinline__ float tanh_fast(float f) {
    f = fminf(fmaxf(f, -15.f), 15.f);
    float e2 = __expf(2.f * f);
    return (e2 - 1.f) / (e2 + 1.f);
}

// ---------------------------------------------------- K1: repack everything
__global__ __launch_bounds__(256) void k1_prep(
    const float* __restrict__ x, const float* __restrict__ start_w,
    const float* __restrict__ filter_w, const float* __restrict__ gate_w,
    const float* __restrict__ res_w, const float* __restrict__ skip_w,
    const float* __restrict__ end1_w, float* __restrict__ ws)
{
    const int id = blockIdx.x, t = threadIdx.x;

    if (id < 80) {
        // fold: M = F * (R_{l-1} + I) -> fp16 blob (R8/R10-proven)
        const int l = id >> 1, m = id & 1;
        __shared__ float F[32][32];
        __shared__ __align__(16) float R[32][36];
        const float* src = m ? gate_w : filter_w;
        for (int e = t; e < 1024; e += 256)
            F[e >> 5][e & 31] = src[(l * 1024 + e) * 2];   // k=0 taps
        if (l > 0)
            for (int e = t; e < 1024; e += 256) {
                const int k = e >> 5, j = e & 31;
                R[k][j] = res_w[(l - 1) * 1024 + e] + (k == j ? 1.f : 0.f);
            }
        __syncthreads();
        const int ch = t >> 3, jg = t & 7, j0 = jg * 4;
        float o0, o1, o2, o3;
        if (l == 0) {
            o0 = F[ch][j0]; o1 = F[ch][j0+1]; o2 = F[ch][j0+2]; o3 = F[ch][j0+3];
        } else {
            o0 = o1 = o2 = o3 = 0.f;
#pragma unroll
            for (int k = 0; k < 32; ++k) {
                const float fv = F[ch][k];
                const float4 rv = *(const float4*)&R[k][j0];
                o0 += fv*rv.x; o1 += fv*rv.y; o2 += fv*rv.z; o3 += fv*rv.w;
            }
        }
        const int hh = jg >> 2;
        __half* dst = (__half*)ws + (size_t)l * 2048 + (hh * 32 + ch) * 32
                    + (m ? 16 : 0) + (j0 & 15);
        ((__half2*)dst)[0] = __floats2half2_rn(o0, o1);
        ((__half2*)dst)[1] = __floats2half2_rn(o2, o3);
    }
    else if (id == 80) {
        // start conv -> c0
        const int b = t >> 5, ch = t & 31;
        float acc = 0.f;
#pragma unroll
        for (int j = 0; j < 6; ++j)
            acc += start_w[ch * 6 + j] * x[(b * 6 + j) * TLEN + TLEN - 1];
        ws[F_C0 + t] = acc;
    }
    else if (id < 241) {
        // skip_w -> fp16, identical layout
        const int q = (id - 81) * 256 + t;           // 0..40959
        const float4* s4 = (const float4*)skip_w;
        const float4 a = s4[q * 2], bb = s4[q * 2 + 1];
        __half2* d = (__half2*)(ws + F_BLOBSK);
        d[q * 4 + 0] = __floats2half2_rn(a.x,  a.y);
        d[q * 4 + 1] = __floats2half2_rn(a.z,  a.w);
        d[q * 4 + 2] = __floats2half2_rn(bb.x, bb.y);
        d[q * 4 + 3] = __floats2half2_rn(bb.z, bb.w);
    }
    else {
        // end1_w -> fp16 transposed: half2[sc2][ec]
        __half2* d = (__half2*)(ws + F_BLOBE1);
#pragma unroll
        for (int k = 0; k < 2; ++k) {
            const int dd = (id - 241) * 512 + k * 256 + t;
            const int ec = dd & 255, sc2 = dd >> 8;
            const float v0 = end1_w[ec * 256 + 2 * sc2];
            const float v1 = end1_w[ec * 256 + 2 * sc2 + 1];
            d[dd] = __floats2half2_rn(v0, v1);
        }
    }
}

// ------------------- K2: free-running recurrence + self-paced consumers ----
#define PF(L, W) do {                                                        \
    if ((L) < NL) {                                                          \
        _Pragma("unroll")                                                    \
        for (int i = 0; i < 4; ++i)                                          \
            W[i] = blobfg[(L) * 256 + lane * 4 + i];                         \
    }                                                                        \
} while (0)

#define SPF(L, SW) do {                                                      \
    if ((L) < NL) {                                                          \
        _Pragma("unroll")                                                    \
        for (int i = 0; i < 4; ++i)                                          \
            SW[i] = blobsk[(L) * 1024 + sc * 4 + i];                         \
    }                                                                        \
} while (0)

// wave0: one recurrence step; z_L lands in ring slot L+1; counter -> L+1
#define K2_STEP(L, W) do {                                                   \
    h2 s[8];                                                                 \
    { const float4* sp = (const float4*)(zring + (L) * 32);                  \
      *(float4*)&s[0] = sp[h * 2];                                           \
      *(float4*)&s[4] = sp[h * 2 + 1]; }                                     \
    float f = 0.f, g = 0.f;                                                  \
    const h2* wfp = (const h2*)&W[0];                                        \
    const h2* wgp = (const h2*)&W[2];                                        \
    _Pragma("unroll")                                                        \
    for (int i = 0; i < 8; ++i) {                                            \
        f = FDOT2(wfp[i], s[i], f);                                          \
        g = FDOT2(wgp[i], s[i], g);                                          \
    }                                                                        \
    f += __shfl_xor(f, 32, 64);                                              \
    g += __shfl_xor(g, 32, 64);                                              \
    const float z = tanh_fast(f) * (1.f / (1.f + __expf(-g)));               \
    if (h == 0) zring[((L) + 1) * 32 + ch] = __float2half(z);                \
    __builtin_amdgcn_wave_barrier();                                         \
    if (lane == 0) *(volatile int*)&prog = (L) + 1;                          \
    __builtin_amdgcn_wave_barrier();                                         \
    PF((L) + 4, W);                                                          \
} while (0)

// consumer: wait for slot L+1, accumulate skip dot, prefetch layer L+2
#define CSTEP(L, SW) do {                                                    \
    while (*(volatile int*)&prog < (L) + 1) {}                               \
    __builtin_amdgcn_wave_barrier();                                         \
    h2 zz[16];                                                               \
    { const float4* zp = (const float4*)(zring + ((L) + 1) * 32);            \
      *(float4*)&zz[0]  = zp[0];  *(float4*)&zz[4]  = zp[1];                 \
      *(float4*)&zz[8]  = zp[2];  *(float4*)&zz[12] = zp[3]; }               \
    const h2* wp = (const h2*)SW;                                            \
    _Pragma("unroll")                                                        \
    for (int i = 0; i < 16; ++i)                                             \
        skip_acc = FDOT2(wp[i], zz[i], skip_acc);                            \
    SPF((L) + 2, SW);                                                        \
} while (0)

__global__ __launch_bounds__(320) void k2_all(
    const float* __restrict__ end1_b, const float* __restrict__ end2_w,
    const float* __restrict__ end2_b, const float* __restrict__ ws,
    float* __restrict__ out)
{
    const int b = blockIdx.x, t = threadIdx.x;
    const int wv = t >> 6, lane = t & 63;
    const int ch = lane & 31, h = lane >> 5;
    const int sc = t - 64;                    // consumer skip channel (wv>=1)

    __shared__ __align__(16) __half zring[(NL + 1) * 32];  // slot0 = c0
    __shared__ __align__(16) __half hhalf[256];
    __shared__ float psum[4];
    __shared__ int prog;

    const float4* blobfg = (const float4*)ws;
    const float4* blobsk = (const float4*)(ws + F_BLOBSK);
    const h2*     blobe1 = (const h2*)(ws + F_BLOBE1);

    float b1 = 0.f, w2 = 0.f, skip_acc = 0.f;

    if (wv == 0 && h == 0)
        zring[ch] = __float2half(ws[F_C0 + b * 32 + ch]);
    if (t == 0) *(volatile int*)&prog = 0;
    __syncthreads();

    if (wv == 0) {
        float4 fg0[4], fg1[4], fg2[4], fg3[4];
        PF(0, fg0); PF(1, fg1); PF(2, fg2); PF(3, fg3);
        for (int l = 0; l < NL; l += 4) {
            K2_STEP(l + 0, fg0);
            K2_STEP(l + 1, fg1);
            K2_STEP(l + 2, fg2);
            K2_STEP(l + 3, fg3);
        }
    } else {
        float4 swA[4], swB[4];
        SPF(0, swA); SPF(1, swB);
        b1 = end1_b[sc];
        w2 = end2_w[sc];
        for (int l = 0; l < NL; l += 2) {
            CSTEP(l + 0, swA);
            CSTEP(l + 1, swB);
        }
        hhalf[sc] = __float2half(fmaxf(skip_acc, 0.f));   // relu(skip_sum)
    }
    __syncthreads();

    // end1 (fp16 from L2, coalesced) + relu + end2 partial (R10-proven)
    if (wv >= 1) {
        float acc = b1;
        const h2* hh2 = (const h2*)hhalf;
#pragma unroll 8
        for (int s2 = 0; s2 < 128; ++s2)
            acc = FDOT2(blobe1[s2 * 256 + sc], hh2[s2], acc);
        float pe = fmaxf(acc, 0.f) * w2;
#pragma unroll
        for (int off = 32; off > 0; off >>= 1)
            pe += __shfl_down(pe, off, 64);
        if (lane == 0) psum[wv - 1] = pe;
    }
    __syncthreads();
    if (t == 64)
        out[b] = psum[0] + psum[1] + psum[2] + psum[3] + end2_b[0];
}

extern "C" void kernel_launch(void* const* d_in, const int* in_sizes, int n_in,
                              void* d_out, int out_size, void* d_ws, size_t ws_size,
                              hipStream_t stream) {
    const float* x        = (const float*)d_in[0];
    const float* start_w  = (const float*)d_in[1];
    const float* filter_w = (const float*)d_in[2];
    const float* gate_w   = (const float*)d_in[3];
    const float* res_w    = (const float*)d_in[4];
    const float* skip_w   = (const float*)d_in[5];
    const float* end1_w   = (const float*)d_in[6];
    const float* end1_b   = (const float*)d_in[7];
    const float* end2_w   = (const float*)d_in[8];
    const float* end2_b   = (const float*)d_in[9];
    float* out = (float*)d_out;
    float* ws  = (float*)d_ws;

    k1_prep<<<305, 256, 0, stream>>>(x, start_w, filter_w, gate_w, res_w,
                                     skip_w, end1_w, ws);
    k2_all <<<8, 320, 0, stream>>>(end1_b, end2_w, end2_b, ws, out);
}